// Round 8
// baseline (517.749 us; speedup 1.0000x reference)
//
#include <hip/hip_runtime.h>
#include <hip/hip_bf16.h>
#include <math.h>

// 3-layer GCN on MI355X.
// R7: build with 4-edge ILP (int4 edge loads, 4 pipelined atomic->store chains)
//     co-scheduled with gemm1 (heterogeneous grid; gemm writes UNSCALED bf16,
//     tiny scale kernel applies rsqrt(deg+1) after). cap 64->48 (slow-path
//     guard covers deg>cap). bf16 staging everywhere; fp32 accumulation.

#define FDIM 64

// ---------- fused: adjacency build (+degree) || layer-1 GEMM (unscaled) ----------
__global__ __launch_bounds__(256) void build_gemm_kernel(
        const int* __restrict__ erow, const int* __restrict__ ecol,
        int* __restrict__ cnt, int* __restrict__ adjF, int e, int cap, int nblkE,
        const float* __restrict__ X, const float* __restrict__ W,
        __hip_bfloat16* __restrict__ Hout, int n) {
    __shared__ float Ws[64][64];
    __shared__ float Xs[64][64];
    const int t = threadIdx.x;

    if ((int)blockIdx.x < nblkE) {
        // ---- build path: 4 edges per thread, pipelined atomics ----
        const int base = (blockIdx.x * 256 + t) * 4;
        if (base + 4 <= e) {
            int4 c4 = *(const int4*)(ecol + base);
            int4 r4 = *(const int4*)(erow + base);
            int q0 = atomicAdd(&cnt[c4.x], 1);
            int q1 = atomicAdd(&cnt[c4.y], 1);
            int q2 = atomicAdd(&cnt[c4.z], 1);
            int q3 = atomicAdd(&cnt[c4.w], 1);
            if (q0 < cap) adjF[(size_t)c4.x * cap + q0] = r4.x;
            if (q1 < cap) adjF[(size_t)c4.y * cap + q1] = r4.y;
            if (q2 < cap) adjF[(size_t)c4.z * cap + q2] = r4.z;
            if (q3 < cap) adjF[(size_t)c4.w * cap + q3] = r4.w;
        } else {
            for (int i = base; i < e; i++) {
                int c = ecol[i];
                int q = atomicAdd(&cnt[c], 1);
                if (q < cap) adjF[(size_t)c * cap + q] = erow[i];
            }
        }
    } else {
        // ---- gemm path: Hout = bf16( X @ W ) (unscaled; dinv applied later) ----
        const int row0 = (blockIdx.x - nblkE) * 64;
        #pragma unroll
        for (int i = t; i < 4096; i += 256) Ws[i >> 6][i & 63] = W[i];
        #pragma unroll
        for (int i = t; i < 4096; i += 256) {
            int r = i >> 6, c = i & 63;
            int gr = row0 + r;
            Xs[r][c] = (gr < n) ? X[(size_t)gr * FDIM + c] : 0.0f;
        }
        __syncthreads();
        const int j = t & 63;
        const int ng = t >> 6;
        float acc[16];
        #pragma unroll
        for (int r = 0; r < 16; r++) acc[r] = 0.0f;
        for (int k = 0; k < 64; k++) {
            float w = Ws[k][j];
            #pragma unroll
            for (int r = 0; r < 16; r++)
                acc[r] += Xs[ng * 16 + r][k] * w;
        }
        #pragma unroll
        for (int r = 0; r < 16; r++) {
            int gr = row0 + ng * 16 + r;
            if (gr < n) Hout[(size_t)gr * FDIM + j] = __float2bfloat16(acc[r]);
        }
    }
}

// ---------- scale: hs[v][:] *= rsqrt(deg[v]+1)  (8 bf16 per thread) ----------
__global__ __launch_bounds__(256) void scale_kernel(__hip_bfloat16* __restrict__ hs,
                                                    const int* __restrict__ cnt, int n) {
    const int tid = blockIdx.x * 256 + threadIdx.x;   // one per 8 features
    if (tid >= n * 8) return;
    const int row = tid >> 3;
    const float dv = rsqrtf((float)cnt[row] + 1.0f);
    __hip_bfloat162* p = (__hip_bfloat162*)(hs + (size_t)row * FDIM + (tid & 7) * 8);
    #pragma unroll
    for (int k = 0; k < 4; k++) {
        __hip_bfloat162 b = p[k];
        b.x = __float2bfloat16(__bfloat162float(b.x) * dv);
        b.y = __float2bfloat16(__bfloat162float(b.y) * dv);
        p[k] = b;
    }
}

// ---------- layers 2/3 GEMM: Hs = bf16( rsqrt(deg+1) * (Z_bf16 @ W) ) ----------
__global__ __launch_bounds__(256) void gemm_bf16_kernel(const __hip_bfloat16* __restrict__ Z,
                                                        const float* __restrict__ W,
                                                        const int* __restrict__ cnt,
                                                        __hip_bfloat16* __restrict__ Hout, int n) {
    __shared__ float Ws[64][64];
    __shared__ float Xs[64][64];
    const int t = threadIdx.x;
    const int row0 = blockIdx.x * 64;
    const __hip_bfloat162* __restrict__ Z2 = (const __hip_bfloat162*)Z;
    #pragma unroll
    for (int i = t; i < 4096; i += 256) Ws[i >> 6][i & 63] = W[i];
    #pragma unroll
    for (int i = t; i < 2048; i += 256) {
        int r = i >> 5, c2 = i & 31;
        int gr = row0 + r;
        float2 v = {0.f, 0.f};
        if (gr < n) {
            __hip_bfloat162 b = Z2[(size_t)gr * 32 + c2];
            v.x = __bfloat162float(b.x);
            v.y = __bfloat162float(b.y);
        }
        Xs[r][2 * c2]     = v.x;
        Xs[r][2 * c2 + 1] = v.y;
    }
    __syncthreads();
    const int j = t & 63;
    const int ng = t >> 6;
    float acc[16];
    #pragma unroll
    for (int r = 0; r < 16; r++) acc[r] = 0.0f;
    for (int k = 0; k < 64; k++) {
        float w = Ws[k][j];
        #pragma unroll
        for (int r = 0; r < 16; r++)
            acc[r] += Xs[ng * 16 + r][k] * w;
    }
    #pragma unroll
    for (int r = 0; r < 16; r++) {
        int gr = row0 + ng * 16 + r;
        if (gr < n) {
            float dv = rsqrtf((float)cnt[gr] + 1.0f);
            Hout[(size_t)gr * FDIM + j] = __float2bfloat16(acc[r] * dv);
        }
    }
}

// ---------- shared gather: sum of pre-scaled neighbor rows (+ self) ----------
__device__ __forceinline__ float2 gather_sum(const __hip_bfloat162* __restrict__ hs2,
                                             const int* __restrict__ adjF,
                                             int v, int deg, int cap, int lane,
                                             const int* __restrict__ erow,
                                             const int* __restrict__ ecol, int etot) {
    const int f2 = lane & 31;
    const int half = lane >> 5;
    float2 a0 = {0.f,0.f}, a1 = {0.f,0.f}, a2 = {0.f,0.f}, a3 = {0.f,0.f};
    float2 a4 = {0.f,0.f}, a5 = {0.f,0.f}, a6 = {0.f,0.f}, a7 = {0.f,0.f};

    if (half == 0) {                       // self loop once
        __hip_bfloat162 sv = hs2[(size_t)v * 32 + f2];
        a0.x = __bfloat162float(sv.x);
        a0.y = __bfloat162float(sv.y);
    }

    if (deg <= cap) {
        const int* __restrict__ av = adjF + (size_t)v * cap;
        for (int base = 0; base < deg; base += 64) {
            int m = deg - base; if (m > 64) m = 64;
            int uvec = 0;
            if (lane < m) uvec = av[base + lane];
            const int pairs = m >> 1;
            int k = 0;
            for (; k + 8 <= pairs; k += 8) {
                int u0 = __shfl(uvec, 2*(k+0) + half, 64);
                int u1 = __shfl(uvec, 2*(k+1) + half, 64);
                int u2 = __shfl(uvec, 2*(k+2) + half, 64);
                int u3 = __shfl(uvec, 2*(k+3) + half, 64);
                int u4 = __shfl(uvec, 2*(k+4) + half, 64);
                int u5 = __shfl(uvec, 2*(k+5) + half, 64);
                int u6 = __shfl(uvec, 2*(k+6) + half, 64);
                int u7 = __shfl(uvec, 2*(k+7) + half, 64);
                __hip_bfloat162 b0 = hs2[(size_t)u0 * 32 + f2];
                __hip_bfloat162 b1 = hs2[(size_t)u1 * 32 + f2];
                __hip_bfloat162 b2 = hs2[(size_t)u2 * 32 + f2];
                __hip_bfloat162 b3 = hs2[(size_t)u3 * 32 + f2];
                __hip_bfloat162 b4 = hs2[(size_t)u4 * 32 + f2];
                __hip_bfloat162 b5 = hs2[(size_t)u5 * 32 + f2];
                __hip_bfloat162 b6 = hs2[(size_t)u6 * 32 + f2];
                __hip_bfloat162 b7 = hs2[(size_t)u7 * 32 + f2];
                a0.x += __bfloat162float(b0.x); a0.y += __bfloat162float(b0.y);
                a1.x += __bfloat162float(b1.x); a1.y += __bfloat162float(b1.y);
                a2.x += __bfloat162float(b2.x); a2.y += __bfloat162float(b2.y);
                a3.x += __bfloat162float(b3.x); a3.y += __bfloat162float(b3.y);
                a4.x += __bfloat162float(b4.x); a4.y += __bfloat162float(b4.y);
                a5.x += __bfloat162float(b5.x); a5.y += __bfloat162float(b5.y);
                a6.x += __bfloat162float(b6.x); a6.y += __bfloat162float(b6.y);
                a7.x += __bfloat162float(b7.x); a7.y += __bfloat162float(b7.y);
            }
            for (; k < pairs; k++) {
                int u = __shfl(uvec, 2*k + half, 64);
                __hip_bfloat162 b = hs2[(size_t)u * 32 + f2];
                a0.x += __bfloat162float(b.x); a0.y += __bfloat162float(b.y);
            }
            if (m & 1) {
                int u = __shfl(uvec, m - 1, 64);
                if (half == 0) {
                    __hip_bfloat162 b = hs2[(size_t)u * 32 + f2];
                    a1.x += __bfloat162float(b.x); a1.y += __bfloat162float(b.y);
                }
            }
        }
    } else {
        // deg > cap (prob ~1e-9/node): wave-cooperative scan of the raw edge list
        for (int base = 0; base < etot; base += 64) {
            int m = etot - base; if (m > 64) m = 64;
            int c = -1, r = 0;
            if (lane < m) { c = ecol[base + lane]; r = erow[base + lane]; }
            unsigned long long mask = __ballot(c == v);
            while (mask) {
                int j = __ffsll((long long)mask) - 1;
                mask &= mask - 1;
                int u = __shfl(r, j, 64);
                if (half == 0) {
                    __hip_bfloat162 b = hs2[(size_t)u * 32 + f2];
                    a0.x += __bfloat162float(b.x); a0.y += __bfloat162float(b.y);
                }
            }
        }
    }

    float2 tot;
    tot.x = ((a0.x + a1.x) + (a2.x + a3.x)) + ((a4.x + a5.x) + (a6.x + a7.x));
    tot.y = ((a0.y + a1.y) + (a2.y + a3.y)) + ((a4.y + a5.y) + (a6.y + a7.y));
    tot.x += __shfl_xor(tot.x, 32, 64);    // combine halves
    tot.y += __shfl_xor(tot.y, 32, 64);
    return tot;
}

// ---------- agg -> z (bias + ELU), bf16 out (layers 1,2) ----------
__global__ __launch_bounds__(256) void agg_z_kernel(const __hip_bfloat16* __restrict__ hs,
                                                    const int* __restrict__ adjF,
                                                    const int* __restrict__ cnt,
                                                    const float* __restrict__ bias,
                                                    __hip_bfloat16* __restrict__ zout,
                                                    int n, int cap,
                                                    const int* __restrict__ erow,
                                                    const int* __restrict__ ecol, int etot) {
    const int v = blockIdx.x * 4 + (threadIdx.x >> 6);
    const int lane = threadIdx.x & 63;
    if (v >= n) return;
    const int f2 = lane & 31;
    const int deg = cnt[v];
    const float dv = rsqrtf((float)deg + 1.0f);
    float2 tot = gather_sum((const __hip_bfloat162*)hs, adjF, v, deg, cap, lane,
                            erow, ecol, etot);
    if ((lane >> 5) == 0) {
        float2 bv = ((const float2*)bias)[f2];
        float rx = tot.x * dv + bv.x;
        float ry = tot.y * dv + bv.y;
        rx = (rx > 0.0f) ? rx : (__expf(rx) - 1.0f);
        ry = (ry > 0.0f) ? ry : (__expf(ry) - 1.0f);
        __hip_bfloat162 o;
        o.x = __float2bfloat16(rx);
        o.y = __float2bfloat16(ry);
        ((__hip_bfloat162*)zout)[(size_t)v * 32 + f2] = o;
    }
}

// ---------- final layer: agg + bias, fp32 out, no ELU ----------
__global__ __launch_bounds__(256) void agg_final_kernel(const __hip_bfloat16* __restrict__ hs,
                                                        const int* __restrict__ adjF,
                                                        const int* __restrict__ cnt,
                                                        const float* __restrict__ bias,
                                                        float* __restrict__ out,
                                                        int n, int cap,
                                                        const int* __restrict__ erow,
                                                        const int* __restrict__ ecol, int etot) {
    const int v = blockIdx.x * 4 + (threadIdx.x >> 6);
    const int lane = threadIdx.x & 63;
    if (v >= n) return;
    const int f2 = lane & 31;
    const int deg = cnt[v];
    const float dv = rsqrtf((float)deg + 1.0f);
    float2 tot = gather_sum((const __hip_bfloat162*)hs, adjF, v, deg, cap, lane,
                            erow, ecol, etot);
    if ((lane >> 5) == 0) {
        float2 bv = ((const float2*)bias)[f2];
        float rx = tot.x * dv + bv.x;
        float ry = tot.y * dv + bv.y;
        ((float2*)out)[(size_t)v * 32 + f2] = make_float2(rx, ry);
    }
}

// ---------- launch ----------

extern "C" void kernel_launch(void* const* d_in, const int* in_sizes, int n_in,
                              void* d_out, int out_size, void* d_ws, size_t ws_size,
                              hipStream_t stream) {
    const float* x   = (const float*)d_in[0];
    const int*   ei  = (const int*)d_in[1];
    const float* W1  = (const float*)d_in[2];
    const float* b1  = (const float*)d_in[3];
    const float* W2  = (const float*)d_in[4];
    const float* b2  = (const float*)d_in[5];
    const float* W3  = (const float*)d_in[6];
    const float* b3  = (const float*)d_in[7];

    const int N = in_sizes[0] / FDIM;      // 100000
    const int E = in_sizes[1] / 2;         // 1600000
    const int* erow = ei;                   // sources
    const int* ecol = ei + E;               // targets

    char* p = (char*)d_ws;
    __hip_bfloat16* hsA = (__hip_bfloat16*)p;  p += (size_t)N * FDIM * sizeof(__hip_bfloat16);
    __hip_bfloat16* zB  = (__hip_bfloat16*)p;  p += (size_t)N * FDIM * sizeof(__hip_bfloat16);
    int* cnt  = (int*)p;  p += (size_t)N * sizeof(int);
    int* adjF = (int*)p;

    // adjacency capacity 48 (P(deg>48)~1e-9/node; slow path guards); degrade if ws small
    size_t used = (size_t)(p - (char*)d_ws);
    int cap = 48;
    if (used + (size_t)N * cap * sizeof(int) > ws_size) cap = 32;

    float* outb = (float*)d_out;

    const int TB = 256;
    const int nblkE = (E + 4 * TB - 1) / (4 * TB);   // build blocks (4 edges/thread)
    const int nblkG = (N + 63) / 64;                 // gemm blocks
    const int nblkA = (N + 3) / 4;
    const int nblkS = (N * 8 + TB - 1) / TB;

    hipMemsetAsync(cnt, 0, (size_t)N * sizeof(int), stream);
    build_gemm_kernel<<<nblkE + nblkG, TB, 0, stream>>>(erow, ecol, cnt, adjF, E, cap, nblkE,
                                                        x, W1, hsA, N);
    scale_kernel<<<nblkS, TB, 0, stream>>>(hsA, cnt, N);
    agg_z_kernel<<<nblkA, TB, 0, stream>>>(hsA, adjF, cnt, b1, zB, N, cap, erow, ecol, E);
    gemm_bf16_kernel<<<nblkG, TB, 0, stream>>>(zB, W2, cnt, hsA, N);
    agg_z_kernel<<<nblkA, TB, 0, stream>>>(hsA, adjF, cnt, b2, zB, N, cap, erow, ecol, E);
    gemm_bf16_kernel<<<nblkG, TB, 0, stream>>>(zB, W3, cnt, hsA, N);
    agg_final_kernel<<<nblkA, TB, 0, stream>>>(hsA, adjF, cnt, b3, outb, N, cap, erow, ecol, E);
}

// Round 9
// 472.585 us; speedup vs baseline: 1.0956x; 1.0956x over previous
//
#include <hip/hip_runtime.h>
#include <hip/hip_bf16.h>
#include <math.h>

// 3-layer GCN on MI355X.
// R8: reconstruct best-measured config (R5, 456us) + verified deltas only:
//     - split build: count_rank (now ILP x4, int4 loads, full occupancy)
//       + atomic-free scatter (adjF[col*cap + rank] = row)
//     - bf16 staging for BOTH hs and inter-layer z (rank aliases zB)
//     - inline rsqrt(deg+1) (no dinv kernel/buffer); cap=64
//     Lessons kept: no wave-matmul fusion (R5 fail), no hetero build||gemm
//     dispatch (R7 fail: occupancy poison).

#define FDIM 64

// ---------- pass 1: histogram + per-edge rank (4 independent chains/thread) ----------
__global__ __launch_bounds__(256) void count_rank_kernel(const int* __restrict__ col,
                                                         int* __restrict__ cnt,
                                                         int* __restrict__ rank, int e) {
    const int base = (blockIdx.x * 256 + threadIdx.x) * 4;
    if (base + 4 <= e) {
        int4 c4 = *(const int4*)(col + base);
        int q0 = atomicAdd(&cnt[c4.x], 1);
        int q1 = atomicAdd(&cnt[c4.y], 1);
        int q2 = atomicAdd(&cnt[c4.z], 1);
        int q3 = atomicAdd(&cnt[c4.w], 1);
        *(int4*)(rank + base) = make_int4(q0, q1, q2, q3);
    } else {
        for (int i = base; i < e; i++)
            rank[i] = atomicAdd(&cnt[col[i]], 1);
    }
}

// ---------- pass 2: atomic-free scatter: adjF[col*cap + rank] = row ----------
__global__ __launch_bounds__(256) void scatter_kernel(const int* __restrict__ row,
                                                      const int* __restrict__ col,
                                                      const int* __restrict__ rank,
                                                      int* __restrict__ adjF, int e, int cap) {
    const int base = (blockIdx.x * 256 + threadIdx.x) * 4;
    if (base + 4 <= e) {
        int4 c4 = *(const int4*)(col + base);
        int4 r4 = *(const int4*)(row + base);
        int4 q4 = *(const int4*)(rank + base);
        if (q4.x < cap) adjF[(size_t)c4.x * cap + q4.x] = r4.x;
        if (q4.y < cap) adjF[(size_t)c4.y * cap + q4.y] = r4.y;
        if (q4.z < cap) adjF[(size_t)c4.z * cap + q4.z] = r4.z;
        if (q4.w < cap) adjF[(size_t)c4.w * cap + q4.w] = r4.w;
    } else {
        for (int i = base; i < e; i++) {
            int q = rank[i];
            if (q < cap) adjF[(size_t)col[i] * cap + q] = row[i];
        }
    }
}

// ---------- layer-1 GEMM: Hs = bf16( rsqrt(deg+1) * (X_f32 @ W) ) ----------
__global__ __launch_bounds__(256) void gemm_f32_kernel(const float* __restrict__ X,
                                                       const float* __restrict__ W,
                                                       const int* __restrict__ cnt,
                                                       __hip_bfloat16* __restrict__ Hout, int n) {
    __shared__ float Ws[64][64];
    __shared__ float Xs[64][64];
    const int t = threadIdx.x;
    const int row0 = blockIdx.x * 64;
    #pragma unroll
    for (int i = t; i < 4096; i += 256) Ws[i >> 6][i & 63] = W[i];
    #pragma unroll
    for (int i = t; i < 4096; i += 256) {
        int r = i >> 6, c = i & 63;
        int gr = row0 + r;
        Xs[r][c] = (gr < n) ? X[(size_t)gr * FDIM + c] : 0.0f;
    }
    __syncthreads();
    const int j = t & 63;
    const int ng = t >> 6;
    float acc[16];
    #pragma unroll
    for (int r = 0; r < 16; r++) acc[r] = 0.0f;
    for (int k = 0; k < 64; k++) {
        float w = Ws[k][j];
        #pragma unroll
        for (int r = 0; r < 16; r++)
            acc[r] += Xs[ng * 16 + r][k] * w;
    }
    #pragma unroll
    for (int r = 0; r < 16; r++) {
        int gr = row0 + ng * 16 + r;
        if (gr < n) {
            float dv = rsqrtf((float)cnt[gr] + 1.0f);
            Hout[(size_t)gr * FDIM + j] = __float2bfloat16(acc[r] * dv);
        }
    }
}

// ---------- layers 2/3 GEMM: Hs = bf16( rsqrt(deg+1) * (Z_bf16 @ W) ) ----------
__global__ __launch_bounds__(256) void gemm_bf16_kernel(const __hip_bfloat16* __restrict__ Z,
                                                        const float* __restrict__ W,
                                                        const int* __restrict__ cnt,
                                                        __hip_bfloat16* __restrict__ Hout, int n) {
    __shared__ float Ws[64][64];
    __shared__ float Xs[64][64];
    const int t = threadIdx.x;
    const int row0 = blockIdx.x * 64;
    const __hip_bfloat162* __restrict__ Z2 = (const __hip_bfloat162*)Z;
    #pragma unroll
    for (int i = t; i < 4096; i += 256) Ws[i >> 6][i & 63] = W[i];
    #pragma unroll
    for (int i = t; i < 2048; i += 256) {
        int r = i >> 5, c2 = i & 31;
        int gr = row0 + r;
        float2 v = {0.f, 0.f};
        if (gr < n) {
            __hip_bfloat162 b = Z2[(size_t)gr * 32 + c2];
            v.x = __bfloat162float(b.x);
            v.y = __bfloat162float(b.y);
        }
        Xs[r][2 * c2]     = v.x;
        Xs[r][2 * c2 + 1] = v.y;
    }
    __syncthreads();
    const int j = t & 63;
    const int ng = t >> 6;
    float acc[16];
    #pragma unroll
    for (int r = 0; r < 16; r++) acc[r] = 0.0f;
    for (int k = 0; k < 64; k++) {
        float w = Ws[k][j];
        #pragma unroll
        for (int r = 0; r < 16; r++)
            acc[r] += Xs[ng * 16 + r][k] * w;
    }
    #pragma unroll
    for (int r = 0; r < 16; r++) {
        int gr = row0 + ng * 16 + r;
        if (gr < n) {
            float dv = rsqrtf((float)cnt[gr] + 1.0f);
            Hout[(size_t)gr * FDIM + j] = __float2bfloat16(acc[r] * dv);
        }
    }
}

// ---------- shared gather: sum of pre-scaled neighbor rows (+ self) ----------
__device__ __forceinline__ float2 gather_sum(const __hip_bfloat162* __restrict__ hs2,
                                             const int* __restrict__ adjF,
                                             int v, int deg, int cap, int lane,
                                             const int* __restrict__ erow,
                                             const int* __restrict__ ecol, int etot) {
    const int f2 = lane & 31;
    const int half = lane >> 5;
    float2 a0 = {0.f,0.f}, a1 = {0.f,0.f}, a2 = {0.f,0.f}, a3 = {0.f,0.f};
    float2 a4 = {0.f,0.f}, a5 = {0.f,0.f}, a6 = {0.f,0.f}, a7 = {0.f,0.f};

    if (half == 0) {                       // self loop once
        __hip_bfloat162 sv = hs2[(size_t)v * 32 + f2];
        a0.x = __bfloat162float(sv.x);
        a0.y = __bfloat162float(sv.y);
    }

    if (deg <= cap) {
        const int* __restrict__ av = adjF + (size_t)v * cap;
        for (int base = 0; base < deg; base += 64) {
            int m = deg - base; if (m > 64) m = 64;
            int uvec = 0;
            if (lane < m) uvec = av[base + lane];
            const int pairs = m >> 1;
            int k = 0;
            for (; k + 8 <= pairs; k += 8) {
                int u0 = __shfl(uvec, 2*(k+0) + half, 64);
                int u1 = __shfl(uvec, 2*(k+1) + half, 64);
                int u2 = __shfl(uvec, 2*(k+2) + half, 64);
                int u3 = __shfl(uvec, 2*(k+3) + half, 64);
                int u4 = __shfl(uvec, 2*(k+4) + half, 64);
                int u5 = __shfl(uvec, 2*(k+5) + half, 64);
                int u6 = __shfl(uvec, 2*(k+6) + half, 64);
                int u7 = __shfl(uvec, 2*(k+7) + half, 64);
                __hip_bfloat162 b0 = hs2[(size_t)u0 * 32 + f2];
                __hip_bfloat162 b1 = hs2[(size_t)u1 * 32 + f2];
                __hip_bfloat162 b2 = hs2[(size_t)u2 * 32 + f2];
                __hip_bfloat162 b3 = hs2[(size_t)u3 * 32 + f2];
                __hip_bfloat162 b4 = hs2[(size_t)u4 * 32 + f2];
                __hip_bfloat162 b5 = hs2[(size_t)u5 * 32 + f2];
                __hip_bfloat162 b6 = hs2[(size_t)u6 * 32 + f2];
                __hip_bfloat162 b7 = hs2[(size_t)u7 * 32 + f2];
                a0.x += __bfloat162float(b0.x); a0.y += __bfloat162float(b0.y);
                a1.x += __bfloat162float(b1.x); a1.y += __bfloat162float(b1.y);
                a2.x += __bfloat162float(b2.x); a2.y += __bfloat162float(b2.y);
                a3.x += __bfloat162float(b3.x); a3.y += __bfloat162float(b3.y);
                a4.x += __bfloat162float(b4.x); a4.y += __bfloat162float(b4.y);
                a5.x += __bfloat162float(b5.x); a5.y += __bfloat162float(b5.y);
                a6.x += __bfloat162float(b6.x); a6.y += __bfloat162float(b6.y);
                a7.x += __bfloat162float(b7.x); a7.y += __bfloat162float(b7.y);
            }
            for (; k < pairs; k++) {
                int u = __shfl(uvec, 2*k + half, 64);
                __hip_bfloat162 b = hs2[(size_t)u * 32 + f2];
                a0.x += __bfloat162float(b.x); a0.y += __bfloat162float(b.y);
            }
            if (m & 1) {
                int u = __shfl(uvec, m - 1, 64);
                if (half == 0) {
                    __hip_bfloat162 b = hs2[(size_t)u * 32 + f2];
                    a1.x += __bfloat162float(b.x); a1.y += __bfloat162float(b.y);
                }
            }
        }
    } else {
        // deg > cap (prob ~2e-18/node at cap=64): wave-cooperative raw-edge scan
        for (int base = 0; base < etot; base += 64) {
            int m = etot - base; if (m > 64) m = 64;
            int c = -1, r = 0;
            if (lane < m) { c = ecol[base + lane]; r = erow[base + lane]; }
            unsigned long long mask = __ballot(c == v);
            while (mask) {
                int j = __ffsll((long long)mask) - 1;
                mask &= mask - 1;
                int u = __shfl(r, j, 64);
                if (half == 0) {
                    __hip_bfloat162 b = hs2[(size_t)u * 32 + f2];
                    a0.x += __bfloat162float(b.x); a0.y += __bfloat162float(b.y);
                }
            }
        }
    }

    float2 tot;
    tot.x = ((a0.x + a1.x) + (a2.x + a3.x)) + ((a4.x + a5.x) + (a6.x + a7.x));
    tot.y = ((a0.y + a1.y) + (a2.y + a3.y)) + ((a4.y + a5.y) + (a6.y + a7.y));
    tot.x += __shfl_xor(tot.x, 32, 64);    // combine halves
    tot.y += __shfl_xor(tot.y, 32, 64);
    return tot;
}

// ---------- agg -> z (bias + ELU), bf16 out (layers 1,2) ----------
__global__ __launch_bounds__(256) void agg_z_kernel(const __hip_bfloat16* __restrict__ hs,
                                                    const int* __restrict__ adjF,
                                                    const int* __restrict__ cnt,
                                                    const float* __restrict__ bias,
                                                    __hip_bfloat16* __restrict__ zout,
                                                    int n, int cap,
                                                    const int* __restrict__ erow,
                                                    const int* __restrict__ ecol, int etot) {
    const int v = blockIdx.x * 4 + (threadIdx.x >> 6);
    const int lane = threadIdx.x & 63;
    if (v >= n) return;
    const int f2 = lane & 31;
    const int deg = cnt[v];
    const float dv = rsqrtf((float)deg + 1.0f);
    float2 tot = gather_sum((const __hip_bfloat162*)hs, adjF, v, deg, cap, lane,
                            erow, ecol, etot);
    if ((lane >> 5) == 0) {
        float2 bv = ((const float2*)bias)[f2];
        float rx = tot.x * dv + bv.x;
        float ry = tot.y * dv + bv.y;
        rx = (rx > 0.0f) ? rx : (__expf(rx) - 1.0f);
        ry = (ry > 0.0f) ? ry : (__expf(ry) - 1.0f);
        __hip_bfloat162 o;
        o.x = __float2bfloat16(rx);
        o.y = __float2bfloat16(ry);
        ((__hip_bfloat162*)zout)[(size_t)v * 32 + f2] = o;
    }
}

// ---------- final layer: agg + bias, fp32 out, no ELU ----------
__global__ __launch_bounds__(256) void agg_final_kernel(const __hip_bfloat16* __restrict__ hs,
                                                        const int* __restrict__ adjF,
                                                        const int* __restrict__ cnt,
                                                        const float* __restrict__ bias,
                                                        float* __restrict__ out,
                                                        int n, int cap,
                                                        const int* __restrict__ erow,
                                                        const int* __restrict__ ecol, int etot) {
    const int v = blockIdx.x * 4 + (threadIdx.x >> 6);
    const int lane = threadIdx.x & 63;
    if (v >= n) return;
    const int f2 = lane & 31;
    const int deg = cnt[v];
    const float dv = rsqrtf((float)deg + 1.0f);
    float2 tot = gather_sum((const __hip_bfloat162*)hs, adjF, v, deg, cap, lane,
                            erow, ecol, etot);
    if ((lane >> 5) == 0) {
        float2 bv = ((const float2*)bias)[f2];
        float rx = tot.x * dv + bv.x;
        float ry = tot.y * dv + bv.y;
        ((float2*)out)[(size_t)v * 32 + f2] = make_float2(rx, ry);
    }
}

// ---------- launch ----------

extern "C" void kernel_launch(void* const* d_in, const int* in_sizes, int n_in,
                              void* d_out, int out_size, void* d_ws, size_t ws_size,
                              hipStream_t stream) {
    const float* x   = (const float*)d_in[0];
    const int*   ei  = (const int*)d_in[1];
    const float* W1  = (const float*)d_in[2];
    const float* b1  = (const float*)d_in[3];
    const float* W2  = (const float*)d_in[4];
    const float* b2  = (const float*)d_in[5];
    const float* W3  = (const float*)d_in[6];
    const float* b3  = (const float*)d_in[7];

    const int N = in_sizes[0] / FDIM;      // 100000
    const int E = in_sizes[1] / 2;         // 1600000
    const int* erow = ei;                   // sources
    const int* ecol = ei + E;               // targets

    char* p = (char*)d_ws;
    __hip_bfloat16* hsA = (__hip_bfloat16*)p;  p += (size_t)N * FDIM * sizeof(__hip_bfloat16);
    __hip_bfloat16* zB  = (__hip_bfloat16*)p;  p += (size_t)N * FDIM * sizeof(__hip_bfloat16);
    int* cnt  = (int*)p;  p += (size_t)N * sizeof(int);
    int* adjF = (int*)p;
    int* rank = (int*)zB;                   // aliased: dead before agg1 writes zB

    // adjacency capacity: biggest of {64,48,32} that fits the workspace
    size_t used = (size_t)(p - (char*)d_ws);
    int cap = 64;
    while (cap > 32 && used + (size_t)N * cap * sizeof(int) > ws_size) cap -= 16;

    float* outb = (float*)d_out;

    const int TB = 256;
    const int nblkE4 = (E + 4 * TB - 1) / (4 * TB);  // 4 edges/thread
    const int nblkG = (N + 63) / 64;
    const int nblkA = (N + 3) / 4;

    hipMemsetAsync(cnt, 0, (size_t)N * sizeof(int), stream);
    count_rank_kernel<<<nblkE4, TB, 0, stream>>>(ecol, cnt, rank, E);
    scatter_kernel<<<nblkE4, TB, 0, stream>>>(erow, ecol, rank, adjF, E, cap);

    gemm_f32_kernel<<<nblkG, TB, 0, stream>>>(x, W1, cnt, hsA, N);
    agg_z_kernel<<<nblkA, TB, 0, stream>>>(hsA, adjF, cnt, b1, zB, N, cap, erow, ecol, E);
    gemm_bf16_kernel<<<nblkG, TB, 0, stream>>>(zB, W2, cnt, hsA, N);
    agg_z_kernel<<<nblkA, TB, 0, stream>>>(hsA, adjF, cnt, b2, zB, N, cap, erow, ecol, E);
    gemm_bf16_kernel<<<nblkG, TB, 0, stream>>>(zB, W3, cnt, hsA, N);
    agg_final_kernel<<<nblkA, TB, 0, stream>>>(hsA, adjF, cnt, b3, outb, N, cap, erow, ecol, E);
}